// Round 4
// baseline (924.229 us; speedup 1.0000x reference)
//
#include <hip/hip_runtime.h>

#define BN_EPS 1e-4f

typedef __attribute__((ext_vector_type(8))) short short8;   // 8 bf16
typedef __attribute__((ext_vector_type(4))) float f32x4;    // MFMA acc
typedef __attribute__((ext_vector_type(4))) float floatv4;
typedef unsigned int uint;

union U4S8 { uint4 u; short8 s; };

// float -> bf16 bits, round-to-nearest-even
static __device__ __forceinline__ unsigned short f2bf(float f) {
    unsigned u = __float_as_uint(f);
    unsigned r = (u + 0x7FFFu + ((u >> 16) & 1u)) >> 16;
    return (unsigned short)r;
}

// ---------------- BN stats over f32 [N,32]: per-channel sum & sumsq -------
__global__ void stats_f32(const float* __restrict__ x,
                          float* __restrict__ stats,   // [64] sum, sumsq
                          int total4) {
    const int t = threadIdx.x;
    long idx = (long)blockIdx.x * 256 + t;
    const long stride = (long)gridDim.x * 256;
    float s[4] = {0.f, 0.f, 0.f, 0.f}, q[4] = {0.f, 0.f, 0.f, 0.f};
    const floatv4* x4 = (const floatv4*)x;
    for (long e = idx; e < total4; e += stride) {
        floatv4 v = x4[e];
#pragma unroll
        for (int j = 0; j < 4; ++j) { s[j] += v[j]; q[j] += v[j] * v[j]; }
    }
    __shared__ float red[256][4];
#pragma unroll
    for (int j = 0; j < 4; ++j) red[t][j] = s[j];
    __syncthreads();
    if (t < 32) {
        float a = 0.f;
        const int grp = t >> 2, j = t & 3;
#pragma unroll
        for (int m = 0; m < 32; ++m) a += red[grp + 8 * m][j];
        atomicAdd(&stats[t], a);
    }
    __syncthreads();
#pragma unroll
    for (int j = 0; j < 4; ++j) red[t][j] = q[j];
    __syncthreads();
    if (t < 32) {
        float a = 0.f;
        const int grp = t >> 2, j = t & 3;
#pragma unroll
        for (int m = 0; m < 32; ++m) a += red[grp + 8 * m][j];
        atomicAdd(&stats[32 + t], a);
    }
}

// ---------------- BN stats over bf16 [N,32] ----------------
__global__ void stats_bf16(const ushort* __restrict__ x,
                           float* __restrict__ stats, int n8) {
    const int t = threadIdx.x;
    long idx = (long)blockIdx.x * 256 + t;
    const long stride = (long)gridDim.x * 256;
    float s[8] = {0}, q[8] = {0};
    const uint4* x8 = (const uint4*)x;
    for (long e = idx; e < n8; e += stride) {
        uint4 v = x8[e];
        uint w0 = v.x, w1 = v.y, w2 = v.z, w3 = v.w;
        float f0 = __uint_as_float(w0 << 16), f1 = __uint_as_float(w0 & 0xFFFF0000u);
        float f2 = __uint_as_float(w1 << 16), f3 = __uint_as_float(w1 & 0xFFFF0000u);
        float f4 = __uint_as_float(w2 << 16), f5 = __uint_as_float(w2 & 0xFFFF0000u);
        float f6 = __uint_as_float(w3 << 16), f7 = __uint_as_float(w3 & 0xFFFF0000u);
        s[0]+=f0; q[0]+=f0*f0; s[1]+=f1; q[1]+=f1*f1;
        s[2]+=f2; q[2]+=f2*f2; s[3]+=f3; q[3]+=f3*f3;
        s[4]+=f4; q[4]+=f4*f4; s[5]+=f5; q[5]+=f5*f5;
        s[6]+=f6; q[6]+=f6*f6; s[7]+=f7; q[7]+=f7*f7;
    }
    __shared__ float red[256][8];
#pragma unroll
    for (int j = 0; j < 8; ++j) red[t][j] = s[j];
    __syncthreads();
    if (t < 32) {
        float a = 0.f;
        const int grp = t >> 3, j = t & 7;
#pragma unroll
        for (int m = 0; m < 64; ++m) a += red[grp + 4 * m][j];
        atomicAdd(&stats[t], a);
    }
    __syncthreads();
#pragma unroll
    for (int j = 0; j < 8; ++j) red[t][j] = q[j];
    __syncthreads();
    if (t < 32) {
        float a = 0.f;
        const int grp = t >> 3, j = t & 7;
#pragma unroll
        for (int m = 0; m < 64; ++m) a += red[grp + 4 * m][j];
        atomicAdd(&stats[32 + t], a);
    }
}

// ---------------- bn_relu + cast to bf16 (f32 input) ----------------
__global__ void bnrelu_f32(const float* __restrict__ x,
                           const float* __restrict__ stats,
                           ushort* __restrict__ xb, int n8, int N) {
    int idx = blockIdx.x * 256 + threadIdx.x;
    if (idx >= n8) return;
    const int c0 = (idx & 3) * 8;
    const float invN = 1.0f / (float)N;
    floatv4 v0 = *(const floatv4*)(x + (size_t)idx * 8);
    floatv4 v1 = *(const floatv4*)(x + (size_t)idx * 8 + 4);
    uint r[8];
#pragma unroll
    for (int j = 0; j < 8; ++j) {
        const int c = c0 + j;
        float mu = stats[c] * invN;
        float var = stats[32 + c] * invN - mu * mu;
        float rs = rsqrtf(var + BN_EPS);
        float f = (j < 4) ? v0[j] : v1[j - 4];
        float xn = fmaxf((f - mu) * rs, 0.f);
        r[j] = (uint)f2bf(xn);
    }
    uint4 o;
    o.x = r[0] | (r[1] << 16); o.y = r[2] | (r[3] << 16);
    o.z = r[4] | (r[5] << 16); o.w = r[6] | (r[7] << 16);
    *(uint4*)(xb + (size_t)idx * 8) = o;
}

// ---------------- bn_relu + cast to bf16 (bf16 input) ----------------
__global__ void bnrelu_bf16(const ushort* __restrict__ h,
                            const float* __restrict__ stats,
                            ushort* __restrict__ xb, int n8, int N) {
    int idx = blockIdx.x * 256 + threadIdx.x;
    if (idx >= n8) return;
    const int c0 = (idx & 3) * 8;
    const float invN = 1.0f / (float)N;
    uint4 v = *(const uint4*)(h + (size_t)idx * 8);
    uint w[4] = {v.x, v.y, v.z, v.w};
    uint r[8];
#pragma unroll
    for (int j = 0; j < 8; ++j) {
        const int c = c0 + j;
        float mu = stats[c] * invN;
        float var = stats[32 + c] * invN - mu * mu;
        float rs = rsqrtf(var + BN_EPS);
        uint bits = (j & 1) ? (w[j >> 1] & 0xFFFF0000u) : (w[j >> 1] << 16);
        float f = __uint_as_float(bits);
        float xn = fmaxf((f - mu) * rs, 0.f);
        r[j] = (uint)f2bf(xn);
    }
    uint4 o;
    o.x = r[0] | (r[1] << 16); o.y = r[2] | (r[3] << 16);
    o.z = r[4] | (r[5] << 16); o.w = r[6] | (r[7] << 16);
    *(uint4*)(xb + (size_t)idx * 8) = o;
}

// ---------------- W [27][cin][cout] f32 -> Wt [27][cout][cin] bf16 --------
__global__ void wcvt(const float* __restrict__ W, ushort* __restrict__ Wt) {
    int idx = blockIdx.x * 256 + threadIdx.x;
    if (idx >= 27 * 1024) return;
    int k = idx >> 10, r = idx & 1023, co = r >> 5, ci = r & 31;
    Wt[(k << 10) + (co << 5) + ci] = f2bf(W[(k << 10) + (ci << 5) + co]);
}

// ---------------- CSR build ----------------
__global__ void histo(const int* __restrict__ pin, const int* __restrict__ pout,
                      uint* __restrict__ cnt, int P) {
    int p = blockIdx.x * 256 + threadIdx.x;
    if (p >= P) return;
    long idx = (long)blockIdx.y * P + p;
    if (pin[idx] >= 0) atomicAdd(&cnt[pout[idx]], 1u);
}

__global__ void scanA(const uint* __restrict__ cnt, uint* __restrict__ bsum, int n) {
    __shared__ uint red[256];
    int base = blockIdx.x * 1024 + threadIdx.x * 4;
    uint s = 0;
#pragma unroll
    for (int j = 0; j < 4; ++j) { int i = base + j; if (i < n) s += cnt[i]; }
    red[threadIdx.x] = s;
    __syncthreads();
    for (int off = 128; off > 0; off >>= 1) {
        if (threadIdx.x < off) red[threadIdx.x] += red[threadIdx.x + off];
        __syncthreads();
    }
    if (threadIdx.x == 0) bsum[blockIdx.x] = red[0];
}

__global__ void scanB(uint* __restrict__ bsum, uint* __restrict__ starts,
                      int nb, int N) {
    __shared__ uint sc[512];
    int t = threadIdx.x;
    sc[t] = (t < nb) ? bsum[t] : 0;
    __syncthreads();
    for (int off = 1; off < 512; off <<= 1) {
        uint v = (t >= off) ? sc[t - off] : 0;
        __syncthreads();
        sc[t] += v;
        __syncthreads();
    }
    if (t < nb) bsum[t] = (t == 0) ? 0 : sc[t - 1];
    if (t == 0) starts[N] = sc[nb - 1];   // total (sentinel)
}

__global__ void scanC(uint* __restrict__ cnt, const uint* __restrict__ bsum,
                      uint* __restrict__ starts, int n) {
    __shared__ uint red[256];
    int t = threadIdx.x;
    int base = blockIdx.x * 1024 + t * 4;
    uint v[4]; uint s = 0;
#pragma unroll
    for (int j = 0; j < 4; ++j) { int i = base + j; v[j] = (i < n) ? cnt[i] : 0; s += v[j]; }
    red[t] = s;
    __syncthreads();
    for (int off = 1; off < 256; off <<= 1) {
        uint y = (t >= off) ? red[t - off] : 0;
        __syncthreads();
        red[t] += y;
        __syncthreads();
    }
    uint run = red[t] - s + bsum[blockIdx.x];   // exclusive prefix
#pragma unroll
    for (int j = 0; j < 4; ++j) {
        int i = base + j;
        if (i < n) { starts[i] = run; cnt[i] = run; run += v[j]; }  // cnt becomes cursor
    }
}

__global__ void fillk(const int* __restrict__ pin, const int* __restrict__ pout,
                      uint* __restrict__ cursor, uint* __restrict__ entries, int P) {
    int p = blockIdx.x * 256 + threadIdx.x;
    if (p >= P) return;
    long idx = (long)blockIdx.y * P + p;
    int i = pin[idx];
    if (i < 0) return;
    uint pos = atomicAdd(&cursor[pout[idx]], 1u);
    entries[pos] = ((uint)blockIdx.y << 25) | (uint)i;
}

// per-output insertion sort by raw u32 => sorted by k (and deterministic)
__global__ void sortk(const uint* __restrict__ starts, uint* __restrict__ entries, int N) {
    int o = blockIdx.x * 256 + threadIdx.x;
    if (o >= N) return;
    uint s = starts[o], e = starts[o + 1];
    for (uint i = s + 1; i < e; ++i) {
        uint key = entries[i];
        uint j = i;
        while (j > s && entries[j - 1] > key) { entries[j] = entries[j - 1]; --j; }
        entries[j] = key;
    }
}

// ------- CSR-gather MFMA conv: wave = 16 outputs, no atomics, no LDS ------
template <bool FINAL>
__global__ void conv_csr(const ushort* __restrict__ xb,
                         const ushort* __restrict__ Wt,    // [27][32 cout][32 cin] bf16
                         const uint* __restrict__ starts,
                         const uint* __restrict__ entries,
                         const float* __restrict__ iden,   // feats (FINAL only)
                         float* __restrict__ outf,         // FINAL
                         ushort* __restrict__ outb,        // !FINAL (bf16)
                         int N) {
    const int w = threadIdx.x >> 6;
    const int tile = blockIdx.x * 4 + w;
    const int o0 = tile * 16;
    if (o0 >= N) return;
    const int l = threadIdx.x & 63;
    const int m = l & 15;     // A-row / C-col (cout)
    const int iq = l >> 4;    // cin chunk iq*8..+7 ; C rows iq*4..+3

    const int o = o0 + m;
    uint q = starts[o];
    const uint e = starts[o + 1];
    uint ent = (q < e) ? entries[q] : 0xFFFFFFFFu;

    f32x4 c0 = {0.f, 0.f, 0.f, 0.f};
    f32x4 c1 = {0.f, 0.f, 0.f, 0.f};

    for (int k = 0; k < 27; ++k) {
        const ushort* wk = Wt + (k << 10);
        U4S8 b0, b1;
        b0.u = *(const uint4*)(wk + m * 32 + iq * 8);
        b1.u = *(const uint4*)(wk + (m + 16) * 32 + iq * 8);

        float a0=0.f,a1=0.f,a2=0.f,a3=0.f,a4=0.f,a5=0.f,a6=0.f,a7=0.f;
        bool got = false;
        while ((ent >> 25) == (uint)k) {
            got = true;
            const uint pin = ent & 0x1FFFFFFu;
            uint4 v = *(const uint4*)(xb + (size_t)pin * 32 + iq * 8);
            a0 += __uint_as_float(v.x << 16);
            a1 += __uint_as_float(v.x & 0xFFFF0000u);
            a2 += __uint_as_float(v.y << 16);
            a3 += __uint_as_float(v.y & 0xFFFF0000u);
            a4 += __uint_as_float(v.z << 16);
            a5 += __uint_as_float(v.z & 0xFFFF0000u);
            a6 += __uint_as_float(v.w << 16);
            a7 += __uint_as_float(v.w & 0xFFFF0000u);
            ++q;
            ent = (q < e) ? entries[q] : 0xFFFFFFFFu;
        }
        if (__any(got)) {
            U4S8 af;
            asm volatile("v_cvt_pk_bf16_f32 %0, %1, %2" : "=v"(af.u.x) : "v"(a0), "v"(a1));
            asm volatile("v_cvt_pk_bf16_f32 %0, %1, %2" : "=v"(af.u.y) : "v"(a2), "v"(a3));
            asm volatile("v_cvt_pk_bf16_f32 %0, %1, %2" : "=v"(af.u.z) : "v"(a4), "v"(a5));
            asm volatile("v_cvt_pk_bf16_f32 %0, %1, %2" : "=v"(af.u.w) : "v"(a6), "v"(a7));
            c0 = __builtin_amdgcn_mfma_f32_16x16x32_bf16(af.s, b0.s, c0, 0, 0, 0);
            c1 = __builtin_amdgcn_mfma_f32_16x16x32_bf16(af.s, b1.s, c1, 0, 0, 0);
        }
    }

    // C write: row r = iq*4 + j, col = m (couts m and m+16), once per output
#pragma unroll
    for (int j = 0; j < 4; ++j) {
        const long ro = (long)(o0 + iq * 4 + j) * 32;
        if (FINAL) {
            outf[ro + m]      = c0[j] + iden[ro + m];
            outf[ro + 16 + m] = c1[j] + iden[ro + 16 + m];
        } else {
            outb[ro + m]      = f2bf(c0[j]);
            outb[ro + 16 + m] = f2bf(c1[j]);
        }
    }
}

// ---------------- downsample scatter-mean ----------------
__global__ void ds_scatter(const float* __restrict__ xyz,
                           const int* __restrict__ batch,
                           const int* __restrict__ din,
                           const int* __restrict__ dout,
                           float* __restrict__ dsum, float* __restrict__ dcnt,
                           int P2n) {
    int p = blockIdx.x * 256 + threadIdx.x;
    if (p >= P2n) return;
    int i = din[p];
    if (i < 0) return;
    int o = dout[p];
    atomicAdd(&dsum[o * 4 + 0], xyz[(long)i * 3 + 0]);
    atomicAdd(&dsum[o * 4 + 1], xyz[(long)i * 3 + 1]);
    atomicAdd(&dsum[o * 4 + 2], xyz[(long)i * 3 + 2]);
    atomicAdd(&dsum[o * 4 + 3], (float)batch[i]);
    atomicAdd(&dcnt[o], 1.0f);
}

__global__ void ds_finalize(const float* __restrict__ dsum,
                            const float* __restrict__ dcnt,
                            float* __restrict__ out_xyz,
                            float* __restrict__ out_batch, int M) {
    int o = blockIdx.x * 256 + threadIdx.x;
    if (o >= M) return;
    float c = fmaxf(dcnt[o], 1.0f);
    float inv = 1.0f / c;
    out_xyz[(long)o * 3 + 0] = dsum[o * 4 + 0] * inv;
    out_xyz[(long)o * 3 + 1] = dsum[o * 4 + 1] * inv;
    out_xyz[(long)o * 3 + 2] = dsum[o * 4 + 2] * inv;
    out_batch[o] = dsum[o * 4 + 3] * inv;
}

extern "C" void kernel_launch(void* const* d_in, const int* in_sizes, int n_in,
                              void* d_out, int out_size, void* d_ws, size_t ws_size,
                              hipStream_t stream) {
    const float* feats = (const float*)d_in[0];
    const float* xyz   = (const float*)d_in[1];
    const int*   batch = (const int*)d_in[2];
    const int*   pin   = (const int*)d_in[3];
    const int*   pout  = (const int*)d_in[4];
    const int*   dsin  = (const int*)d_in[5];
    const int*   dsout = (const int*)d_in[6];
    const float* W1    = (const float*)d_in[7];
    const float* W2    = (const float*)d_in[8];

    const int N   = in_sizes[0] / 32;
    const int K   = 27;
    const int P   = in_sizes[3] / K;
    const int P2n = in_sizes[5];
    const int M   = (out_size - N * 32) / 4;

    auto align256 = [](size_t x) { return (x + 255) & ~(size_t)255; };
    char* base = (char*)d_ws;
    size_t off = 0;
    float* stats1 = (float*)(base + off); off += 256;
    float* stats2 = (float*)(base + off); off += 256;
    float* dsum   = (float*)(base + off); off += (size_t)M * 16;
    float* dcnt   = (float*)(base + off); off = align256(off + (size_t)M * 4);
    uint*  cnt    = (uint*)(base + off);  off += (size_t)N * 4;   // count -> cursor
    const size_t zero_end = off;
    off = align256(off);
    uint*  starts = (uint*)(base + off);  off = align256(off + (size_t)(N + 1) * 4);
    const int nb = (N + 1023) / 1024;
    uint*  bsum   = (uint*)(base + off);  off = align256(off + (size_t)nb * 4);
    uint*  entries= (uint*)(base + off);  off = align256(off + (size_t)K * P * 4);
    ushort* Wt1   = (ushort*)(base + off); off = align256(off + 27 * 1024 * 2);
    ushort* Wt2   = (ushort*)(base + off); off = align256(off + 27 * 1024 * 2);
    ushort* xb    = (ushort*)(base + off); off = align256(off + (size_t)N * 64);
    ushort* hacc  = (ushort*)(base + off); off = align256(off + (size_t)N * 64);

    hipMemsetAsync(d_ws, 0, zero_end, stream);

    // W -> bf16 transposed
    wcvt<<<108, 256, 0, stream>>>(W1, Wt1);
    wcvt<<<108, 256, 0, stream>>>(W2, Wt2);

    // CSR build (shared by both convs)
    dim3 pg((P + 255) / 256, K);
    histo<<<pg, 256, 0, stream>>>(pin, pout, cnt, P);
    scanA<<<nb, 256, 0, stream>>>(cnt, bsum, N);
    scanB<<<1, 512, 0, stream>>>(bsum, starts, nb, N);
    scanC<<<nb, 256, 0, stream>>>(cnt, bsum, starts, N);
    fillk<<<pg, 256, 0, stream>>>(pin, pout, cnt, entries, P);
    sortk<<<(N + 255) / 256, 256, 0, stream>>>(starts, entries, N);

    // conv1: bn_relu(feats) -> W1 -> hacc (bf16)
    stats_f32<<<1024, 256, 0, stream>>>(feats, stats1, N * 8);
    bnrelu_f32<<<(N * 4 + 255) / 256, 256, 0, stream>>>(feats, stats1, xb, N * 4, N);
    const int cblocks = (N / 16 + 3) / 4;
    conv_csr<false><<<cblocks, 256, 0, stream>>>(xb, Wt1, starts, entries,
                                                 nullptr, nullptr, hacc, N);

    // conv2: bn_relu(hacc) -> W2 -> out (+ identity feats)
    stats_bf16<<<1024, 256, 0, stream>>>(hacc, stats2, N * 4);
    bnrelu_bf16<<<(N * 4 + 255) / 256, 256, 0, stream>>>(hacc, stats2, xb, N * 4, N);
    float* out = (float*)d_out;
    conv_csr<true><<<cblocks, 256, 0, stream>>>(xb, Wt2, starts, entries,
                                                feats, out, nullptr, N);

    // downsample scatter-mean
    ds_scatter<<<(P2n + 255) / 256, 256, 0, stream>>>(xyz, batch, dsin, dsout,
                                                      dsum, dcnt, P2n);
    ds_finalize<<<(M + 255) / 256, 256, 0, stream>>>(dsum, dcnt,
                                                     out + (size_t)N * 32,
                                                     out + (size_t)N * 32 + (size_t)3 * M,
                                                     M);
}

// Round 5
// 909.999 us; speedup vs baseline: 1.0156x; 1.0156x over previous
//
#include <hip/hip_runtime.h>

#define BN_EPS 1e-4f
#define CPAD 16   // uints per counter slot = 64B (own cache line)

typedef __attribute__((ext_vector_type(8))) short short8;   // 8 bf16
typedef __attribute__((ext_vector_type(4))) float f32x4;    // MFMA acc
typedef __attribute__((ext_vector_type(4))) float floatv4;
typedef unsigned int uint;

union U4S8 { uint4 u; short8 s; };

// float -> bf16 bits, round-to-nearest-even
static __device__ __forceinline__ unsigned short f2bf(float f) {
    unsigned u = __float_as_uint(f);
    unsigned r = (u + 0x7FFFu + ((u >> 16) & 1u)) >> 16;
    return (unsigned short)r;
}

// ---------------- BN stats over f32 [N,32]: per-channel sum & sumsq -------
__global__ void stats_f32(const float* __restrict__ x,
                          float* __restrict__ stats, int total4) {
    const int t = threadIdx.x;
    long idx = (long)blockIdx.x * 256 + t;
    const long stride = (long)gridDim.x * 256;
    float s[4] = {0.f, 0.f, 0.f, 0.f}, q[4] = {0.f, 0.f, 0.f, 0.f};
    const floatv4* x4 = (const floatv4*)x;
    for (long e = idx; e < total4; e += stride) {
        floatv4 v = x4[e];
#pragma unroll
        for (int j = 0; j < 4; ++j) { s[j] += v[j]; q[j] += v[j] * v[j]; }
    }
    __shared__ float red[256][4];
#pragma unroll
    for (int j = 0; j < 4; ++j) red[t][j] = s[j];
    __syncthreads();
    if (t < 32) {
        float a = 0.f;
        const int grp = t >> 2, j = t & 3;
#pragma unroll
        for (int m = 0; m < 32; ++m) a += red[grp + 8 * m][j];
        atomicAdd(&stats[t], a);
    }
    __syncthreads();
#pragma unroll
    for (int j = 0; j < 4; ++j) red[t][j] = q[j];
    __syncthreads();
    if (t < 32) {
        float a = 0.f;
        const int grp = t >> 2, j = t & 3;
#pragma unroll
        for (int m = 0; m < 32; ++m) a += red[grp + 8 * m][j];
        atomicAdd(&stats[32 + t], a);
    }
}

// ---------------- BN stats over bf16 [N,32] ----------------
__global__ void stats_bf16(const ushort* __restrict__ x,
                           float* __restrict__ stats, int n8) {
    const int t = threadIdx.x;
    long idx = (long)blockIdx.x * 256 + t;
    const long stride = (long)gridDim.x * 256;
    float s[8] = {0}, q[8] = {0};
    const uint4* x8 = (const uint4*)x;
    for (long e = idx; e < n8; e += stride) {
        uint4 v = x8[e];
        uint w0 = v.x, w1 = v.y, w2 = v.z, w3 = v.w;
        float f0 = __uint_as_float(w0 << 16), f1 = __uint_as_float(w0 & 0xFFFF0000u);
        float f2 = __uint_as_float(w1 << 16), f3 = __uint_as_float(w1 & 0xFFFF0000u);
        float f4 = __uint_as_float(w2 << 16), f5 = __uint_as_float(w2 & 0xFFFF0000u);
        float f6 = __uint_as_float(w3 << 16), f7 = __uint_as_float(w3 & 0xFFFF0000u);
        s[0]+=f0; q[0]+=f0*f0; s[1]+=f1; q[1]+=f1*f1;
        s[2]+=f2; q[2]+=f2*f2; s[3]+=f3; q[3]+=f3*f3;
        s[4]+=f4; q[4]+=f4*f4; s[5]+=f5; q[5]+=f5*f5;
        s[6]+=f6; q[6]+=f6*f6; s[7]+=f7; q[7]+=f7*f7;
    }
    __shared__ float red[256][8];
#pragma unroll
    for (int j = 0; j < 8; ++j) red[t][j] = s[j];
    __syncthreads();
    if (t < 32) {
        float a = 0.f;
        const int grp = t >> 3, j = t & 7;
#pragma unroll
        for (int m = 0; m < 64; ++m) a += red[grp + 4 * m][j];
        atomicAdd(&stats[t], a);
    }
    __syncthreads();
#pragma unroll
    for (int j = 0; j < 8; ++j) red[t][j] = q[j];
    __syncthreads();
    if (t < 32) {
        float a = 0.f;
        const int grp = t >> 3, j = t & 7;
#pragma unroll
        for (int m = 0; m < 64; ++m) a += red[grp + 4 * m][j];
        atomicAdd(&stats[32 + t], a);
    }
}

// ---------------- bn_relu + cast to bf16 (f32 input) ----------------
__global__ void bnrelu_f32(const float* __restrict__ x,
                           const float* __restrict__ stats,
                           ushort* __restrict__ xb, int n8, int N) {
    int idx = blockIdx.x * 256 + threadIdx.x;
    if (idx >= n8) return;
    const int c0 = (idx & 3) * 8;
    const float invN = 1.0f / (float)N;
    floatv4 v0 = *(const floatv4*)(x + (size_t)idx * 8);
    floatv4 v1 = *(const floatv4*)(x + (size_t)idx * 8 + 4);
    uint r[8];
#pragma unroll
    for (int j = 0; j < 8; ++j) {
        const int c = c0 + j;
        float mu = stats[c] * invN;
        float var = stats[32 + c] * invN - mu * mu;
        float rs = rsqrtf(var + BN_EPS);
        float f = (j < 4) ? v0[j] : v1[j - 4];
        float xn = fmaxf((f - mu) * rs, 0.f);
        r[j] = (uint)f2bf(xn);
    }
    uint4 o;
    o.x = r[0] | (r[1] << 16); o.y = r[2] | (r[3] << 16);
    o.z = r[4] | (r[5] << 16); o.w = r[6] | (r[7] << 16);
    *(uint4*)(xb + (size_t)idx * 8) = o;
}

// ---------------- bn_relu + cast to bf16 (bf16 input) ----------------
__global__ void bnrelu_bf16(const ushort* __restrict__ h,
                            const float* __restrict__ stats,
                            ushort* __restrict__ xb, int n8, int N) {
    int idx = blockIdx.x * 256 + threadIdx.x;
    if (idx >= n8) return;
    const int c0 = (idx & 3) * 8;
    const float invN = 1.0f / (float)N;
    uint4 v = *(const uint4*)(h + (size_t)idx * 8);
    uint w[4] = {v.x, v.y, v.z, v.w};
    uint r[8];
#pragma unroll
    for (int j = 0; j < 8; ++j) {
        const int c = c0 + j;
        float mu = stats[c] * invN;
        float var = stats[32 + c] * invN - mu * mu;
        float rs = rsqrtf(var + BN_EPS);
        uint bits = (j & 1) ? (w[j >> 1] & 0xFFFF0000u) : (w[j >> 1] << 16);
        float f = __uint_as_float(bits);
        float xn = fmaxf((f - mu) * rs, 0.f);
        r[j] = (uint)f2bf(xn);
    }
    uint4 o;
    o.x = r[0] | (r[1] << 16); o.y = r[2] | (r[3] << 16);
    o.z = r[4] | (r[5] << 16); o.w = r[6] | (r[7] << 16);
    *(uint4*)(xb + (size_t)idx * 8) = o;
}

// ---------------- W [27][cin][cout] f32 -> Wt [27][cout][cin] bf16 --------
__global__ void wcvt(const float* __restrict__ W, ushort* __restrict__ Wt) {
    int idx = blockIdx.x * 256 + threadIdx.x;
    if (idx >= 27 * 1024) return;
    int k = idx >> 10, r = idx & 1023, co = r >> 5, ci = r & 31;
    Wt[(k << 10) + (co << 5) + ci] = f2bf(W[(k << 10) + (ci << 5) + co]);
}

// ---------------- CSR build (padded counters: 1 per 64B line) -------------
__global__ void histo(const int* __restrict__ pin, const int* __restrict__ pout,
                      uint* __restrict__ cnt_pad, int P) {
    int p = blockIdx.x * 256 + threadIdx.x;
    if (p >= P) return;
    long idx = (long)blockIdx.y * P + p;
    if (pin[idx] >= 0) atomicAdd(&cnt_pad[(size_t)pout[idx] * CPAD], 1u);
}

__global__ void scanA(const uint* __restrict__ cnt_pad, uint* __restrict__ bsum, int n) {
    __shared__ uint red[256];
    int base = blockIdx.x * 1024 + threadIdx.x * 4;
    uint s = 0;
#pragma unroll
    for (int j = 0; j < 4; ++j) { int i = base + j; if (i < n) s += cnt_pad[(size_t)i * CPAD]; }
    red[threadIdx.x] = s;
    __syncthreads();
    for (int off = 128; off > 0; off >>= 1) {
        if (threadIdx.x < off) red[threadIdx.x] += red[threadIdx.x + off];
        __syncthreads();
    }
    if (threadIdx.x == 0) bsum[blockIdx.x] = red[0];
}

__global__ void scanB(uint* __restrict__ bsum, uint* __restrict__ starts,
                      int nb, int N) {
    __shared__ uint sc[512];
    int t = threadIdx.x;
    sc[t] = (t < nb) ? bsum[t] : 0;
    __syncthreads();
    for (int off = 1; off < 512; off <<= 1) {
        uint v = (t >= off) ? sc[t - off] : 0;
        __syncthreads();
        sc[t] += v;
        __syncthreads();
    }
    if (t < nb) bsum[t] = (t == 0) ? 0 : sc[t - 1];
    if (t == 0) starts[N] = sc[nb - 1];   // total (sentinel)
}

// cnt_pad counts -> starts (dense exclusive prefix) + cnt_pad becomes cursor
__global__ void scanC(uint* __restrict__ cnt_pad, const uint* __restrict__ bsum,
                      uint* __restrict__ starts, int n) {
    __shared__ uint red[256];
    int t = threadIdx.x;
    int base = blockIdx.x * 1024 + t * 4;
    uint v[4]; uint s = 0;
#pragma unroll
    for (int j = 0; j < 4; ++j) { int i = base + j; v[j] = (i < n) ? cnt_pad[(size_t)i * CPAD] : 0; s += v[j]; }
    red[t] = s;
    __syncthreads();
    for (int off = 1; off < 256; off <<= 1) {
        uint y = (t >= off) ? red[t - off] : 0;
        __syncthreads();
        red[t] += y;
        __syncthreads();
    }
    uint run = red[t] - s + bsum[blockIdx.x];   // exclusive prefix
#pragma unroll
    for (int j = 0; j < 4; ++j) {
        int i = base + j;
        if (i < n) { starts[i] = run; cnt_pad[(size_t)i * CPAD] = run; run += v[j]; }
    }
}

__global__ void fillk(const int* __restrict__ pin, const int* __restrict__ pout,
                      uint* __restrict__ cursor_pad, uint* __restrict__ entries, int P) {
    int p = blockIdx.x * 256 + threadIdx.x;
    if (p >= P) return;
    long idx = (long)blockIdx.y * P + p;
    int i = pin[idx];
    if (i < 0) return;
    uint pos = atomicAdd(&cursor_pad[(size_t)pout[idx] * CPAD], 1u);
    entries[pos] = ((uint)blockIdx.y << 25) | (uint)i;
}

// ------- CSR-gather MFMA conv: wave = 16 outputs; LDS-staged, LDS-sorted ---
// entries for outputs o0..o0+15 are CONTIGUOUS -> coalesced cooperative load.
template <bool FINAL>
__global__ void conv_csr(const ushort* __restrict__ xb,
                         const ushort* __restrict__ Wt,    // [27][32 cout][32 cin]
                         const uint* __restrict__ starts,
                         const uint* __restrict__ entries,
                         const float* __restrict__ iden,
                         float* __restrict__ outf,
                         ushort* __restrict__ outb,
                         int N) {
    const int w  = threadIdx.x >> 6;
    const int l  = threadIdx.x & 63;
    const int m  = l & 15;     // output-within-tile / C col (cout)
    const int iq = l >> 4;     // cin chunk iq*8..+7 ; C rows iq*4..+3
    const int o0 = (blockIdx.x * 4 + w) * 16;

    __shared__ uint eld[4][384];

    const bool tv = (o0 < N);           // N%16==0 -> whole tile valid
    uint s0 = 0, sm = 0, se = 0, total = 0;
    if (tv) {
        s0 = starts[o0];
        sm = starts[o0 + m];
        se = starts[o0 + m + 1];
        total = starts[o0 + 16] - s0;
        if (total > 384) total = 384;   // statistically unreachable
        for (uint t = l; t < total; t += 64)
            eld[w][t] = entries[s0 + t];
    }
    __syncthreads();

    // per-lane insertion sort of its list (groups by k; u32 order)
    if (tv && iq == 0) {
        const uint a = sm - s0, b = se - s0;
        for (uint i = a + 1; i < b; ++i) {
            uint key = eld[w][i];
            uint j = i;
            while (j > a && eld[w][j - 1] > key) { eld[w][j] = eld[w][j - 1]; --j; }
            eld[w][j] = key;
        }
    }
    __syncthreads();

    f32x4 c0 = {0.f, 0.f, 0.f, 0.f};
    f32x4 c1 = {0.f, 0.f, 0.f, 0.f};

    uint q = sm - s0;
    const uint e = se - s0;
    uint ent = (tv && q < e) ? eld[w][q] : 0xFFFFFFFFu;

    for (int k = 0; k < 27; ++k) {
        const ushort* wk = Wt + (k << 10);
        U4S8 b0, b1;
        b0.u = *(const uint4*)(wk + m * 32 + iq * 8);
        b1.u = *(const uint4*)(wk + (m + 16) * 32 + iq * 8);

        float a0=0.f,a1=0.f,a2=0.f,a3=0.f,a4=0.f,a5=0.f,a6=0.f,a7=0.f;
        bool got = false;
        while ((ent >> 25) == (uint)k) {
            got = true;
            const uint pi = ent & 0x1FFFFFFu;
            uint4 v = *(const uint4*)(xb + (size_t)pi * 32 + iq * 8);
            a0 += __uint_as_float(v.x << 16);
            a1 += __uint_as_float(v.x & 0xFFFF0000u);
            a2 += __uint_as_float(v.y << 16);
            a3 += __uint_as_float(v.y & 0xFFFF0000u);
            a4 += __uint_as_float(v.z << 16);
            a5 += __uint_as_float(v.z & 0xFFFF0000u);
            a6 += __uint_as_float(v.w << 16);
            a7 += __uint_as_float(v.w & 0xFFFF0000u);
            ++q;
            ent = (q < e) ? eld[w][q] : 0xFFFFFFFFu;
        }
        if (__any(got)) {
            U4S8 af;
            asm volatile("v_cvt_pk_bf16_f32 %0, %1, %2" : "=v"(af.u.x) : "v"(a0), "v"(a1));
            asm volatile("v_cvt_pk_bf16_f32 %0, %1, %2" : "=v"(af.u.y) : "v"(a2), "v"(a3));
            asm volatile("v_cvt_pk_bf16_f32 %0, %1, %2" : "=v"(af.u.z) : "v"(a4), "v"(a5));
            asm volatile("v_cvt_pk_bf16_f32 %0, %1, %2" : "=v"(af.u.w) : "v"(a6), "v"(a7));
            c0 = __builtin_amdgcn_mfma_f32_16x16x32_bf16(af.s, b0.s, c0, 0, 0, 0);
            c1 = __builtin_amdgcn_mfma_f32_16x16x32_bf16(af.s, b1.s, c1, 0, 0, 0);
        }
    }

    if (tv) {
#pragma unroll
        for (int j = 0; j < 4; ++j) {
            const long ro = (long)(o0 + iq * 4 + j) * 32;
            if (FINAL) {
                outf[ro + m]      = c0[j] + iden[ro + m];
                outf[ro + 16 + m] = c1[j] + iden[ro + 16 + m];
            } else {
                outb[ro + m]      = f2bf(c0[j]);
                outb[ro + 16 + m] = f2bf(c1[j]);
            }
        }
    }
}

// ---------------- downsample scatter-mean ----------------
__global__ void ds_scatter(const float* __restrict__ xyz,
                           const int* __restrict__ batch,
                           const int* __restrict__ din,
                           const int* __restrict__ dout,
                           float* __restrict__ dsum, float* __restrict__ dcnt,
                           int P2n) {
    int p = blockIdx.x * 256 + threadIdx.x;
    if (p >= P2n) return;
    int i = din[p];
    if (i < 0) return;
    int o = dout[p];
    atomicAdd(&dsum[o * 4 + 0], xyz[(long)i * 3 + 0]);
    atomicAdd(&dsum[o * 4 + 1], xyz[(long)i * 3 + 1]);
    atomicAdd(&dsum[o * 4 + 2], xyz[(long)i * 3 + 2]);
    atomicAdd(&dsum[o * 4 + 3], (float)batch[i]);
    atomicAdd(&dcnt[o], 1.0f);
}

__global__ void ds_finalize(const float* __restrict__ dsum,
                            const float* __restrict__ dcnt,
                            float* __restrict__ out_xyz,
                            float* __restrict__ out_batch, int M) {
    int o = blockIdx.x * 256 + threadIdx.x;
    if (o >= M) return;
    float c = fmaxf(dcnt[o], 1.0f);
    float inv = 1.0f / c;
    out_xyz[(long)o * 3 + 0] = dsum[o * 4 + 0] * inv;
    out_xyz[(long)o * 3 + 1] = dsum[o * 4 + 1] * inv;
    out_xyz[(long)o * 3 + 2] = dsum[o * 4 + 2] * inv;
    out_batch[o] = dsum[o * 4 + 3] * inv;
}

extern "C" void kernel_launch(void* const* d_in, const int* in_sizes, int n_in,
                              void* d_out, int out_size, void* d_ws, size_t ws_size,
                              hipStream_t stream) {
    const float* feats = (const float*)d_in[0];
    const float* xyz   = (const float*)d_in[1];
    const int*   batch = (const int*)d_in[2];
    const int*   pin   = (const int*)d_in[3];
    const int*   pout  = (const int*)d_in[4];
    const int*   dsin  = (const int*)d_in[5];
    const int*   dsout = (const int*)d_in[6];
    const float* W1    = (const float*)d_in[7];
    const float* W2    = (const float*)d_in[8];

    const int N   = in_sizes[0] / 32;
    const int K   = 27;
    const int P   = in_sizes[3] / K;
    const int P2n = in_sizes[5];
    const int M   = (out_size - N * 32) / 4;

    auto align256 = [](size_t x) { return (x + 255) & ~(size_t)255; };
    char* base = (char*)d_ws;
    size_t off = 0;
    float* stats1 = (float*)(base + off); off += 256;
    float* stats2 = (float*)(base + off); off += 256;
    float* dsum   = (float*)(base + off); off += (size_t)M * 16;
    float* dcnt   = (float*)(base + off); off = align256(off + (size_t)M * 4);
    uint*  cnt_pad= (uint*)(base + off);  off += (size_t)N * CPAD * 4;  // 64B/counter
    const size_t zero_end = off;
    off = align256(off);
    uint*  starts = (uint*)(base + off);  off = align256(off + (size_t)(N + 1) * 4);
    const int nb = (N + 1023) / 1024;
    uint*  bsum   = (uint*)(base + off);  off = align256(off + (size_t)nb * 4);
    uint*  entries= (uint*)(base + off);  off = align256(off + (size_t)K * P * 4);
    ushort* Wt1   = (ushort*)(base + off); off = align256(off + 27 * 1024 * 2);
    ushort* Wt2   = (ushort*)(base + off); off = align256(off + 27 * 1024 * 2);
    ushort* xb    = (ushort*)(base + off); off = align256(off + (size_t)N * 64);
    ushort* hacc  = (ushort*)(base + off); off = align256(off + (size_t)N * 64);

    hipMemsetAsync(d_ws, 0, zero_end, stream);

    // W -> bf16 transposed
    wcvt<<<108, 256, 0, stream>>>(W1, Wt1);
    wcvt<<<108, 256, 0, stream>>>(W2, Wt2);

    // CSR build (shared by both convs)
    dim3 pg((P + 255) / 256, K);
    histo<<<pg, 256, 0, stream>>>(pin, pout, cnt_pad, P);
    scanA<<<nb, 256, 0, stream>>>(cnt_pad, bsum, N);
    scanB<<<1, 512, 0, stream>>>(bsum, starts, nb, N);
    scanC<<<nb, 256, 0, stream>>>(cnt_pad, bsum, starts, N);
    fillk<<<pg, 256, 0, stream>>>(pin, pout, cnt_pad, entries, P);

    // conv1: bn_relu(feats) -> W1 -> hacc (bf16)
    stats_f32<<<1024, 256, 0, stream>>>(feats, stats1, N * 8);
    bnrelu_f32<<<(N * 4 + 255) / 256, 256, 0, stream>>>(feats, stats1, xb, N * 4, N);
    const int cblocks = (N / 16 + 3) / 4;
    conv_csr<false><<<cblocks, 256, 0, stream>>>(xb, Wt1, starts, entries,
                                                 nullptr, nullptr, hacc, N);

    // conv2: bn_relu(hacc) -> W2 -> out (+ identity feats)
    stats_bf16<<<1024, 256, 0, stream>>>(hacc, stats2, N * 4);
    bnrelu_bf16<<<(N * 4 + 255) / 256, 256, 0, stream>>>(hacc, stats2, xb, N * 4, N);
    float* out = (float*)d_out;
    conv_csr<true><<<cblocks, 256, 0, stream>>>(xb, Wt2, starts, entries,
                                                feats, out, nullptr, N);

    // downsample scatter-mean
    ds_scatter<<<(P2n + 255) / 256, 256, 0, stream>>>(xyz, batch, dsin, dsout,
                                                      dsum, dcnt, P2n);
    ds_finalize<<<(M + 255) / 256, 256, 0, stream>>>(dsum, dcnt,
                                                     out + (size_t)N * 32,
                                                     out + (size_t)N * 32 + (size_t)3 * M,
                                                     M);
}

// Round 6
// 628.843 us; speedup vs baseline: 1.4697x; 1.4471x over previous
//
#include <hip/hip_runtime.h>

#define BN_EPS 1e-4f
#define BKT_SH 7          // 128 outputs per bucket
#define NBUCK_MAX 2560
#define CBLK 256          // blocks in count/place phases
#define LDSCAP 15872      // max records per place-block
#define P3CAP 2048        // max records per bucket

typedef __attribute__((ext_vector_type(8))) short short8;   // 8 bf16
typedef __attribute__((ext_vector_type(4))) float f32x4;    // MFMA acc
typedef __attribute__((ext_vector_type(4))) float floatv4;
typedef unsigned int uint;

union U4S8 { uint4 u; short8 s; };

// float -> bf16 bits, round-to-nearest-even
static __device__ __forceinline__ unsigned short f2bf(float f) {
    unsigned u = __float_as_uint(f);
    unsigned r = (u + 0x7FFFu + ((u >> 16) & 1u)) >> 16;
    return (unsigned short)r;
}

// ---------------- BN stats over f32 [N,32]: per-channel sum & sumsq -------
__global__ void stats_f32(const float* __restrict__ x,
                          float* __restrict__ stats, int total4) {
    const int t = threadIdx.x;
    long idx = (long)blockIdx.x * 256 + t;
    const long stride = (long)gridDim.x * 256;
    float s[4] = {0.f, 0.f, 0.f, 0.f}, q[4] = {0.f, 0.f, 0.f, 0.f};
    const floatv4* x4 = (const floatv4*)x;
    for (long e = idx; e < total4; e += stride) {
        floatv4 v = x4[e];
#pragma unroll
        for (int j = 0; j < 4; ++j) { s[j] += v[j]; q[j] += v[j] * v[j]; }
    }
    __shared__ float red[256][4];
#pragma unroll
    for (int j = 0; j < 4; ++j) red[t][j] = s[j];
    __syncthreads();
    if (t < 32) {
        float a = 0.f;
        const int grp = t >> 2, j = t & 3;
#pragma unroll
        for (int m = 0; m < 32; ++m) a += red[grp + 8 * m][j];
        atomicAdd(&stats[t], a);
    }
    __syncthreads();
#pragma unroll
    for (int j = 0; j < 4; ++j) red[t][j] = q[j];
    __syncthreads();
    if (t < 32) {
        float a = 0.f;
        const int grp = t >> 2, j = t & 3;
#pragma unroll
        for (int m = 0; m < 32; ++m) a += red[grp + 8 * m][j];
        atomicAdd(&stats[32 + t], a);
    }
}

// ---------------- BN stats over bf16 [N,32] ----------------
__global__ void stats_bf16(const ushort* __restrict__ x,
                           float* __restrict__ stats, int n8) {
    const int t = threadIdx.x;
    long idx = (long)blockIdx.x * 256 + t;
    const long stride = (long)gridDim.x * 256;
    float s[8] = {0}, q[8] = {0};
    const uint4* x8 = (const uint4*)x;
    for (long e = idx; e < n8; e += stride) {
        uint4 v = x8[e];
        uint w0 = v.x, w1 = v.y, w2 = v.z, w3 = v.w;
        float f0 = __uint_as_float(w0 << 16), f1 = __uint_as_float(w0 & 0xFFFF0000u);
        float f2 = __uint_as_float(w1 << 16), f3 = __uint_as_float(w1 & 0xFFFF0000u);
        float f4 = __uint_as_float(w2 << 16), f5 = __uint_as_float(w2 & 0xFFFF0000u);
        float f6 = __uint_as_float(w3 << 16), f7 = __uint_as_float(w3 & 0xFFFF0000u);
        s[0]+=f0; q[0]+=f0*f0; s[1]+=f1; q[1]+=f1*f1;
        s[2]+=f2; q[2]+=f2*f2; s[3]+=f3; q[3]+=f3*f3;
        s[4]+=f4; q[4]+=f4*f4; s[5]+=f5; q[5]+=f5*f5;
        s[6]+=f6; q[6]+=f6*f6; s[7]+=f7; q[7]+=f7*f7;
    }
    __shared__ float red[256][8];
#pragma unroll
    for (int j = 0; j < 8; ++j) red[t][j] = s[j];
    __syncthreads();
    if (t < 32) {
        float a = 0.f;
        const int grp = t >> 3, j = t & 7;
#pragma unroll
        for (int m = 0; m < 64; ++m) a += red[grp + 4 * m][j];
        atomicAdd(&stats[t], a);
    }
    __syncthreads();
#pragma unroll
    for (int j = 0; j < 8; ++j) red[t][j] = q[j];
    __syncthreads();
    if (t < 32) {
        float a = 0.f;
        const int grp = t >> 3, j = t & 7;
#pragma unroll
        for (int m = 0; m < 64; ++m) a += red[grp + 4 * m][j];
        atomicAdd(&stats[32 + t], a);
    }
}

// ---------------- bn_relu + cast to bf16 (f32 input) ----------------
__global__ void bnrelu_f32(const float* __restrict__ x,
                           const float* __restrict__ stats,
                           ushort* __restrict__ xb, int n8, int N) {
    int idx = blockIdx.x * 256 + threadIdx.x;
    if (idx >= n8) return;
    const int c0 = (idx & 3) * 8;
    const float invN = 1.0f / (float)N;
    floatv4 v0 = *(const floatv4*)(x + (size_t)idx * 8);
    floatv4 v1 = *(const floatv4*)(x + (size_t)idx * 8 + 4);
    uint r[8];
#pragma unroll
    for (int j = 0; j < 8; ++j) {
        const int c = c0 + j;
        float mu = stats[c] * invN;
        float var = stats[32 + c] * invN - mu * mu;
        float rs = rsqrtf(var + BN_EPS);
        float f = (j < 4) ? v0[j] : v1[j - 4];
        float xn = fmaxf((f - mu) * rs, 0.f);
        r[j] = (uint)f2bf(xn);
    }
    uint4 o;
    o.x = r[0] | (r[1] << 16); o.y = r[2] | (r[3] << 16);
    o.z = r[4] | (r[5] << 16); o.w = r[6] | (r[7] << 16);
    *(uint4*)(xb + (size_t)idx * 8) = o;
}

// ---------------- bn_relu + cast to bf16 (bf16 input) ----------------
__global__ void bnrelu_bf16(const ushort* __restrict__ h,
                            const float* __restrict__ stats,
                            ushort* __restrict__ xb, int n8, int N) {
    int idx = blockIdx.x * 256 + threadIdx.x;
    if (idx >= n8) return;
    const int c0 = (idx & 3) * 8;
    const float invN = 1.0f / (float)N;
    uint4 v = *(const uint4*)(h + (size_t)idx * 8);
    uint w[4] = {v.x, v.y, v.z, v.w};
    uint r[8];
#pragma unroll
    for (int j = 0; j < 8; ++j) {
        const int c = c0 + j;
        float mu = stats[c] * invN;
        float var = stats[32 + c] * invN - mu * mu;
        float rs = rsqrtf(var + BN_EPS);
        uint bits = (j & 1) ? (w[j >> 1] & 0xFFFF0000u) : (w[j >> 1] << 16);
        float f = __uint_as_float(bits);
        float xn = fmaxf((f - mu) * rs, 0.f);
        r[j] = (uint)f2bf(xn);
    }
    uint4 o;
    o.x = r[0] | (r[1] << 16); o.y = r[2] | (r[3] << 16);
    o.z = r[4] | (r[5] << 16); o.w = r[6] | (r[7] << 16);
    *(uint4*)(xb + (size_t)idx * 8) = o;
}

// ---------------- W [27][cin][cout] f32 -> Wt [27][cout][cin] bf16 --------
__global__ void wcvt(const float* __restrict__ W, ushort* __restrict__ Wt) {
    int idx = blockIdx.x * 256 + threadIdx.x;
    if (idx >= 27 * 1024) return;
    int k = idx >> 10, r = idx & 1023, co = r >> 5, ci = r & 31;
    Wt[(k << 10) + (co << 5) + ci] = f2bf(W[(k << 10) + (ci << 5) + co]);
}

// ============ CSR build: atomic-free MSD bucket sort ============
// bucket = pout >> 7 (128 outputs each). Record payload = (k<<19)|pin (24b).

// phase 1: per-block LDS histogram over buckets -> cntmat[block][bucket]
__global__ void p1_count(const int* __restrict__ pin, const int* __restrict__ pout,
                         uint* __restrict__ cntmat, int KP, int chunk, int nbuck) {
    __shared__ uint H[NBUCK_MAX];
    const int t = threadIdx.x;
    for (int i = t; i < nbuck; i += 256) H[i] = 0;
    __syncthreads();
    const int r0 = blockIdx.x * chunk;
    const int r1 = min(KP, r0 + chunk);
    for (int r = r0 + t; r < r1; r += 256)
        if (pin[r] >= 0) atomicAdd(&H[((uint)pout[r]) >> BKT_SH], 1u);
    __syncthreads();
    uint* row = cntmat + (size_t)blockIdx.x * nbuck;
    for (int i = t; i < nbuck; i += 256) row[i] = H[i];
}

// phase 2: per-bucket exclusive scan over blocks (in place) + bucket totals
__global__ void p2_colscan(uint* __restrict__ cntmat, uint* __restrict__ btot,
                           int nbuck) {
    const int b = blockIdx.x;
    const int t = threadIdx.x;
    __shared__ uint sh[256];
    uint v = cntmat[(size_t)t * nbuck + b];
    sh[t] = v;
    __syncthreads();
    for (int off = 1; off < 256; off <<= 1) {
        uint y = (t >= off) ? sh[t - off] : 0;
        __syncthreads();
        sh[t] += y;
        __syncthreads();
    }
    cntmat[(size_t)t * nbuck + b] = sh[t] - v;   // exclusive over blocks
    if (t == 255) btot[b] = sh[255];
}

// phase 3: exclusive scan of bucket totals -> bbase; sentinel + starts[N]
__global__ void p3_bucketscan(const uint* __restrict__ btot, uint* __restrict__ bbase,
                              uint* __restrict__ starts, int nbuck, int N) {
    const int t = threadIdx.x;
    __shared__ uint part[256];
    uint loc[10]; uint s = 0;
#pragma unroll
    for (int u = 0; u < 10; ++u) {
        int i = t * 10 + u;
        loc[u] = (i < nbuck) ? btot[i] : 0;
        s += loc[u];
    }
    part[t] = s;
    __syncthreads();
    for (int off = 1; off < 256; off <<= 1) {
        uint y = (t >= off) ? part[t - off] : 0;
        __syncthreads();
        part[t] += y;
        __syncthreads();
    }
    uint run = part[t] - s;
#pragma unroll
    for (int u = 0; u < 10; ++u) {
        int i = t * 10 + u;
        if (i < nbuck) { bbase[i] = run; run += loc[u]; }
    }
    if (t == 255) { bbase[nbuck] = run; starts[N] = run; }
}

// phase 4: counting-sort block's records by bucket in LDS, write bucket runs
__global__ __launch_bounds__(256, 1)
void p4_place(const int* __restrict__ pin, const int* __restrict__ pout,
              const uint* __restrict__ cntmat, const uint* __restrict__ bbase,
              uint* __restrict__ tmp, int KP, int P, int chunk, int nbuck) {
    __shared__ uint recs[LDSCAP];
    __shared__ uint H[NBUCK_MAX + 1];
    __shared__ uint C[NBUCK_MAX];
    __shared__ uint part[256];
    const int t = threadIdx.x;
    const int j = blockIdx.x;
    for (int i = t; i < nbuck; i += 256) H[i] = 0;
    __syncthreads();
    const int r0 = j * chunk;
    const int r1 = min(KP, r0 + chunk);
    for (int r = r0 + t; r < r1; r += 256)
        if (pin[r] >= 0) atomicAdd(&H[((uint)pout[r]) >> BKT_SH], 1u);
    __syncthreads();
    // exclusive scan H in place; total -> H[nbuck]
    uint loc[10]; uint s = 0;
#pragma unroll
    for (int u = 0; u < 10; ++u) {
        int i = t * 10 + u;
        loc[u] = (i < nbuck) ? H[i] : 0;
        s += loc[u];
    }
    __syncthreads();
    part[t] = s;
    __syncthreads();
    for (int off = 1; off < 256; off <<= 1) {
        uint y = (t >= off) ? part[t - off] : 0;
        __syncthreads();
        part[t] += y;
        __syncthreads();
    }
    uint run = part[t] - s;
#pragma unroll
    for (int u = 0; u < 10; ++u) {
        int i = t * 10 + u;
        if (i < nbuck) { uint c = loc[u]; H[i] = run; run += c; }
    }
    if (t == 255) H[nbuck] = run;
    __syncthreads();
    for (int i = t; i < nbuck; i += 256) C[i] = H[i];   // cursors
    __syncthreads();
    // place records sorted-by-bucket into LDS
    for (int r = r0 + t; r < r1; r += 256) {
        int ii = pin[r];
        if (ii < 0) continue;
        uint po = (uint)pout[r];
        uint b = po >> BKT_SH;
        uint k = (uint)r / (uint)P;
        uint pos = atomicAdd(&C[b], 1u);
        recs[pos] = ((po & 127u) << 24) | (k << 19) | (uint)ii;
    }
    __syncthreads();
    const uint tot = H[nbuck];
    for (int i = t; i < nbuck; i += 256)
        C[i] = bbase[i] + cntmat[(size_t)j * nbuck + i] - H[i];  // dest bias
    __syncthreads();
    // write runs: consecutive s within a bucket -> consecutive global slots
    for (uint sdx = t; sdx < tot; sdx += 256) {
        uint lo = 0, hi = (uint)nbuck;           // find b: H[b] <= sdx < H[b+1]
        while (hi - lo > 1) { uint mid = (lo + hi) >> 1; if (H[mid] <= sdx) lo = mid; else hi = mid; }
        tmp[C[lo] + sdx] = recs[sdx];
    }
}

// phase 5: per-bucket counting-sort by output -> starts + entries
__global__ void p5_fine(const uint* __restrict__ tmp, const uint* __restrict__ bbase,
                        uint* __restrict__ entries, uint* __restrict__ starts, int N) {
    __shared__ uint recs[P3CAP];
    __shared__ uint cnt[128];
    __shared__ uint curl[128];
    const int b = blockIdx.x;
    const int t = threadIdx.x;
    const uint e0 = bbase[b];
    uint nrec = bbase[b + 1] - e0;
    if (nrec > P3CAP) nrec = P3CAP;
    for (uint s = t; s < nrec; s += 256) recs[s] = tmp[e0 + s];
    if (t < 128) { cnt[t] = 0; curl[t] = 0; }
    __syncthreads();
    for (uint s = t; s < nrec; s += 256) atomicAdd(&cnt[recs[s] >> 24], 1u);
    __syncthreads();
    uint orig = (t < 128) ? cnt[t] : 0;
    for (int off = 1; off < 128; off <<= 1) {
        uint y = (t < 128 && t >= off) ? cnt[t - off] : 0;
        __syncthreads();
        if (t < 128) cnt[t] += y;
        __syncthreads();
    }
    if (t < 128) cnt[t] -= orig;   // exclusive prefix per local output
    __syncthreads();
    const int o0 = b << BKT_SH;
    if (t < 128 && o0 + t < N) starts[o0 + t] = e0 + cnt[t];
    for (uint s = t; s < nrec; s += 256) {
        uint lo = recs[s] >> 24;
        uint idx = atomicAdd(&curl[lo], 1u);
        entries[e0 + cnt[lo] + idx] = recs[s] & 0x00FFFFFFu;
    }
}

// ------- CSR-gather MFMA conv: wave = 16 outputs; LDS-staged, LDS-sorted ---
// entry = (k<<19)|pin, 24 bits. Lists per output sorted in LDS by value.
template <bool FINAL>
__global__ void conv_csr(const ushort* __restrict__ xb,
                         const ushort* __restrict__ Wt,    // [27][32 cout][32 cin]
                         const uint* __restrict__ starts,
                         const uint* __restrict__ entries,
                         const float* __restrict__ iden,
                         float* __restrict__ outf,
                         ushort* __restrict__ outb,
                         int N) {
    const int w  = threadIdx.x >> 6;
    const int l  = threadIdx.x & 63;
    const int m  = l & 15;     // output-within-tile / C col (cout)
    const int iq = l >> 4;     // cin chunk iq*8..+7 ; C rows iq*4..+3
    const int o0 = (blockIdx.x * 4 + w) * 16;

    __shared__ uint eld[4][384];

    const bool tv = (o0 < N);
    uint s0 = 0, sm = 0, se = 0, total = 0;
    if (tv) {
        s0 = starts[o0];
        sm = starts[o0 + m];
        se = starts[o0 + m + 1];
        total = starts[o0 + 16] - s0;
        if (total > 384) total = 384;
        for (uint t = l; t < total; t += 64)
            eld[w][t] = entries[s0 + t];
    }
    __syncthreads();

    // per-lane insertion sort of its list (groups by k; u32 order)
    if (tv && iq == 0) {
        const uint a = sm - s0, bnd = se - s0;
        for (uint i = a + 1; i < bnd; ++i) {
            uint key = eld[w][i];
            uint j = i;
            while (j > a && eld[w][j - 1] > key) { eld[w][j] = eld[w][j - 1]; --j; }
            eld[w][j] = key;
        }
    }
    __syncthreads();

    f32x4 c0 = {0.f, 0.f, 0.f, 0.f};
    f32x4 c1 = {0.f, 0.f, 0.f, 0.f};

    uint q = sm - s0;
    const uint e = se - s0;
    uint ent = (tv && q < e) ? eld[w][q] : 0xFFFFFFFFu;

    for (int k = 0; k < 27; ++k) {
        const ushort* wk = Wt + (k << 10);
        U4S8 b0, b1;
        b0.u = *(const uint4*)(wk + m * 32 + iq * 8);
        b1.u = *(const uint4*)(wk + (m + 16) * 32 + iq * 8);

        float a0=0.f,a1=0.f,a2=0.f,a3=0.f,a4=0.f,a5=0.f,a6=0.f,a7=0.f;
        bool got = false;
        while ((ent >> 19) == (uint)k) {
            got = true;
            const uint pi = ent & 0x7FFFFu;
            uint4 v = *(const uint4*)(xb + (size_t)pi * 32 + iq * 8);
            a0 += __uint_as_float(v.x << 16);
            a1 += __uint_as_float(v.x & 0xFFFF0000u);
            a2 += __uint_as_float(v.y << 16);
            a3 += __uint_as_float(v.y & 0xFFFF0000u);
            a4 += __uint_as_float(v.z << 16);
            a5 += __uint_as_float(v.z & 0xFFFF0000u);
            a6 += __uint_as_float(v.w << 16);
            a7 += __uint_as_float(v.w & 0xFFFF0000u);
            ++q;
            ent = (q < e) ? eld[w][q] : 0xFFFFFFFFu;
        }
        if (__any(got)) {
            U4S8 af;
            asm volatile("v_cvt_pk_bf16_f32 %0, %1, %2" : "=v"(af.u.x) : "v"(a0), "v"(a1));
            asm volatile("v_cvt_pk_bf16_f32 %0, %1, %2" : "=v"(af.u.y) : "v"(a2), "v"(a3));
            asm volatile("v_cvt_pk_bf16_f32 %0, %1, %2" : "=v"(af.u.z) : "v"(a4), "v"(a5));
            asm volatile("v_cvt_pk_bf16_f32 %0, %1, %2" : "=v"(af.u.w) : "v"(a6), "v"(a7));
            c0 = __builtin_amdgcn_mfma_f32_16x16x32_bf16(af.s, b0.s, c0, 0, 0, 0);
            c1 = __builtin_amdgcn_mfma_f32_16x16x32_bf16(af.s, b1.s, c1, 0, 0, 0);
        }
    }

    if (tv) {
#pragma unroll
        for (int j = 0; j < 4; ++j) {
            const long ro = (long)(o0 + iq * 4 + j) * 32;
            if (FINAL) {
                outf[ro + m]      = c0[j] + iden[ro + m];
                outf[ro + 16 + m] = c1[j] + iden[ro + 16 + m];
            } else {
                outb[ro + m]      = f2bf(c0[j]);
                outb[ro + 16 + m] = f2bf(c1[j]);
            }
        }
    }
}

// ---------------- downsample scatter-mean ----------------
__global__ void ds_scatter(const float* __restrict__ xyz,
                           const int* __restrict__ batch,
                           const int* __restrict__ din,
                           const int* __restrict__ dout,
                           float* __restrict__ dsum, float* __restrict__ dcnt,
                           int P2n) {
    int p = blockIdx.x * 256 + threadIdx.x;
    if (p >= P2n) return;
    int i = din[p];
    if (i < 0) return;
    int o = dout[p];
    atomicAdd(&dsum[o * 4 + 0], xyz[(long)i * 3 + 0]);
    atomicAdd(&dsum[o * 4 + 1], xyz[(long)i * 3 + 1]);
    atomicAdd(&dsum[o * 4 + 2], xyz[(long)i * 3 + 2]);
    atomicAdd(&dsum[o * 4 + 3], (float)batch[i]);
    atomicAdd(&dcnt[o], 1.0f);
}

__global__ void ds_finalize(const float* __restrict__ dsum,
                            const float* __restrict__ dcnt,
                            float* __restrict__ out_xyz,
                            float* __restrict__ out_batch, int M) {
    int o = blockIdx.x * 256 + threadIdx.x;
    if (o >= M) return;
    float c = fmaxf(dcnt[o], 1.0f);
    float inv = 1.0f / c;
    out_xyz[(long)o * 3 + 0] = dsum[o * 4 + 0] * inv;
    out_xyz[(long)o * 3 + 1] = dsum[o * 4 + 1] * inv;
    out_xyz[(long)o * 3 + 2] = dsum[o * 4 + 2] * inv;
    out_batch[o] = dsum[o * 4 + 3] * inv;
}

extern "C" void kernel_launch(void* const* d_in, const int* in_sizes, int n_in,
                              void* d_out, int out_size, void* d_ws, size_t ws_size,
                              hipStream_t stream) {
    const float* feats = (const float*)d_in[0];
    const float* xyz   = (const float*)d_in[1];
    const int*   batch = (const int*)d_in[2];
    const int*   pin   = (const int*)d_in[3];
    const int*   pout  = (const int*)d_in[4];
    const int*   dsin  = (const int*)d_in[5];
    const int*   dsout = (const int*)d_in[6];
    const float* W1    = (const float*)d_in[7];
    const float* W2    = (const float*)d_in[8];

    const int N   = in_sizes[0] / 32;
    const int K   = 27;
    const int P   = in_sizes[3] / K;
    const int KP  = K * P;
    const int P2n = in_sizes[5];
    const int M   = (out_size - N * 32) / 4;
    const int nbuck = (N + 127) >> BKT_SH;       // 2344 for N=300000
    const int chunk = (KP + CBLK - 1) / CBLK;    // 15821 <= LDSCAP

    auto align256 = [](size_t x) { return (x + 255) & ~(size_t)255; };
    char* base = (char*)d_ws;
    size_t off = 0;
    float* stats1 = (float*)(base + off); off += 256;
    float* stats2 = (float*)(base + off); off += 256;
    float* dsum   = (float*)(base + off); off += (size_t)M * 16;
    float* dcnt   = (float*)(base + off); off = align256(off + (size_t)M * 4);
    const size_t zero_end = off;
    uint* cntmat  = (uint*)(base + off);  off = align256(off + (size_t)CBLK * nbuck * 4);
    uint* btot    = (uint*)(base + off);  off = align256(off + (size_t)nbuck * 4);
    uint* bbase   = (uint*)(base + off);  off = align256(off + (size_t)(nbuck + 1) * 4);
    uint* starts  = (uint*)(base + off);  off = align256(off + (size_t)(N + 1) * 4);
    uint* tmp     = (uint*)(base + off);  off = align256(off + (size_t)KP * 4);
    uint* entries = (uint*)(base + off);  off = align256(off + (size_t)KP * 4);
    ushort* Wt1   = (ushort*)(base + off); off = align256(off + 27 * 1024 * 2);
    ushort* Wt2   = (ushort*)(base + off); off = align256(off + 27 * 1024 * 2);
    ushort* xb    = (ushort*)(base + off); off = align256(off + (size_t)N * 64);
    ushort* hacc  = (ushort*)(base + off); off = align256(off + (size_t)N * 64);

    hipMemsetAsync(d_ws, 0, zero_end, stream);

    // W -> bf16 transposed
    wcvt<<<108, 256, 0, stream>>>(W1, Wt1);
    wcvt<<<108, 256, 0, stream>>>(W2, Wt2);

    // CSR build (atomic-free; shared by both convs)
    p1_count<<<CBLK, 256, 0, stream>>>(pin, pout, cntmat, KP, chunk, nbuck);
    p2_colscan<<<nbuck, 256, 0, stream>>>(cntmat, btot, nbuck);
    p3_bucketscan<<<1, 256, 0, stream>>>(btot, bbase, starts, nbuck, N);
    p4_place<<<CBLK, 256, 0, stream>>>(pin, pout, cntmat, bbase, tmp, KP, P, chunk, nbuck);
    p5_fine<<<nbuck, 256, 0, stream>>>(tmp, bbase, entries, starts, N);

    // conv1: bn_relu(feats) -> W1 -> hacc (bf16)
    stats_f32<<<1024, 256, 0, stream>>>(feats, stats1, N * 8);
    bnrelu_f32<<<(N * 4 + 255) / 256, 256, 0, stream>>>(feats, stats1, xb, N * 4, N);
    const int cblocks = (N / 16 + 3) / 4;
    conv_csr<false><<<cblocks, 256, 0, stream>>>(xb, Wt1, starts, entries,
                                                 nullptr, nullptr, hacc, N);

    // conv2: bn_relu(hacc) -> W2 -> out (+ identity feats)
    stats_bf16<<<1024, 256, 0, stream>>>(hacc, stats2, N * 4);
    bnrelu_bf16<<<(N * 4 + 255) / 256, 256, 0, stream>>>(hacc, stats2, xb, N * 4, N);
    float* out = (float*)d_out;
    conv_csr<true><<<cblocks, 256, 0, stream>>>(xb, Wt2, starts, entries,
                                                feats, out, nullptr, N);

    // downsample scatter-mean
    ds_scatter<<<(P2n + 255) / 256, 256, 0, stream>>>(xyz, batch, dsin, dsout,
                                                      dsum, dcnt, P2n);
    ds_finalize<<<(M + 255) / 256, 256, 0, stream>>>(dsum, dcnt,
                                                     out + (size_t)N * 32,
                                                     out + (size_t)N * 32 + (size_t)3 * M,
                                                     M);
}